// Round 13
// baseline (69.028 us; speedup 1.0000x reference)
//
#include <hip/hip_runtime.h>
#include <hip/hip_fp16.h>

#define N_NODES 100000
#define N_EDGES 600000
#define DIM 128
#define HID 64
#define NCHUNK 1563          // ceil(100000 / 64); 1563 = 3 * 521

typedef __attribute__((ext_vector_type(8))) _Float16 half8;
typedef __attribute__((ext_vector_type(4))) _Float16 half4v;
typedef __attribute__((ext_vector_type(4))) float floatx4;

// ---------------------------------------------------------------------------
// Kernel 0: W1T[c][k] (f16, [128][128]) = c<64 ? W1[k][c] : W1[128+k][c-64]
// ---------------------------------------------------------------------------
__global__ __launch_bounds__(256) void prep_W(
    const float* __restrict__ W1, __half* __restrict__ W1T)
{
    const int o = (int)(blockIdx.x * blockDim.x + threadIdx.x) * 2;
    if (o >= 128 * 128) return;
    const int c = o >> 7, k = o & 127;
    float w0, w1;
    if (c < HID) { w0 = W1[k * HID + c];               w1 = W1[(k + 1) * HID + c]; }
    else         { w0 = W1[(DIM + k) * HID + c - HID]; w1 = W1[(DIM + k + 1) * HID + c - HID]; }
    W1T[o]     = __float2half(w0);
    W1T[o + 1] = __float2half(w1);
}

// ---------------------------------------------------------------------------
// Kernel 1 (v8): REG-STAGED contiguous loads. Per chunk (64 rows, 32 KB):
// thread t, round r loads global bytes [chunk + r*4096 + t*16, +16) -- a
// wave covers 1024 B linear, identical pattern to the 6.3 TB/s copy bench.
// After the current chunk's MFMA phase: vmcnt(0), then ds_write_b128 to the
// XOR-swizzled LDS address (source linear, swizzle on LDS side). Compute +
// permuted packed epilogue identical to R5. 521 blocks x 3 chunks exact.
// ---------------------------------------------------------------------------
__global__ __launch_bounds__(256, 2) void precompute_P(
    const float* __restrict__ node_emb,
    const __half* __restrict__ W1T,
    const float* __restrict__ b1,
    __half* __restrict__ P)
{
    __shared__ char Abuf[2][64 * 512];           // 2 x 32 KB

    const int tid  = threadIdx.x;
    const int w    = tid >> 6;
    const int lane = tid & 63;
    const int lr   = lane & 15;
    const int q    = lane >> 4;

    // W fragments (full 128 cols) -- same as R5 (no pin; R5 was fastest)
    half8 wf[8][4];
#pragma unroll
    for (int nt = 0; nt < 8; nt++)
#pragma unroll
        for (int ks = 0; ks < 4; ks++)
            wf[nt][ks] = *(const half8*)(W1T + (size_t)(nt * 16 + lr) * 128 + ks * 32 + q * 8);

    float bias_[4][4];
#pragma unroll
    for (int nt = 0; nt < 4; nt++) {
        const float4 b4 = *(const float4*)(b1 + nt * 16 + q * 4);
        bias_[nt][0] = b4.x; bias_[nt][1] = b4.y;
        bias_[nt][2] = b4.z; bias_[nt][3] = b4.w;
    }

    // staging geometry: round r covers rows r*8 .. r*8+7 of the chunk;
    // thread t covers row (r*8 + (t>>5)), bytes (t&31)*16.
    const int srow = tid >> 5;                   // row-in-group 0..7
    const int sbyt = (tid & 31) << 4;            // byte within 512-B row
    // swizzled LDS byte offset for this thread's 16-B piece in round r:
    //   row_in = r*8 + srow ; lds = row_in*512 + (sbyt ^ ((row_in&7)<<4))
    const int ldsoff = srow * 512 + (sbyt ^ ((srow & 7) << 4));  // + r*4096

    const char* nb = (const char*)node_emb;
    const int b = (int)blockIdx.x;

    // chunk list: b, b+521, b+1042 (exactly 3 each)
    float4 g[8];

    // ---- prologue: load chunk b into regs, write to buf 0
#pragma unroll
    for (int r = 0; r < 8; r++) {
        int grow = b * 64 + r * 8 + srow;
        if (grow >= N_NODES) grow = N_NODES - 1;
        g[r] = *(const float4*)(nb + (size_t)grow * 512 + sbyt);
    }
    asm volatile("s_waitcnt vmcnt(0)" ::: "memory");
    __builtin_amdgcn_sched_barrier(0);
#pragma unroll
    for (int r = 0; r < 8; r++)
        *(float4*)(&Abuf[0][0] + r * 4096 + ldsoff) = g[r];
    asm volatile("s_waitcnt lgkmcnt(0)" ::: "memory");
    __builtin_amdgcn_s_barrier();

    int cur = 0;
#pragma unroll 1
    for (int i = 0; i < 3; i++, cur ^= 1) {
        const int c = b + i * 521;

        // 1) issue next chunk's loads (contiguous) BEFORE compute
        if (i < 2) {
            const int cn = b + (i + 1) * 521;
#pragma unroll
            for (int r = 0; r < 8; r++) {
                int grow = cn * 64 + r * 8 + srow;
                if (grow >= N_NODES) grow = N_NODES - 1;
                g[r] = *(const float4*)(nb + (size_t)grow * 512 + sbyt);
            }
            __builtin_amdgcn_sched_barrier(0);   // pin issue point
        }

        // 2) compute chunk c from Abuf[cur]
        floatx4 acc[8];
#pragma unroll
        for (int nt = 0; nt < 8; nt++) acc[nt] = (floatx4){0.f, 0.f, 0.f, 0.f};

        const char* Ab = &Abuf[cur][0];
        const int rb = w * 16 + lr;
        const int sw = (rb & 7) << 4;
#pragma unroll
        for (int ks = 0; ks < 4; ks++) {
            const int cb = ks * 128 + q * 32;
            const float4 x0 = *(const float4*)(Ab + rb * 512 + ((cb)      ^ sw));
            const float4 x1 = *(const float4*)(Ab + rb * 512 + ((cb + 16) ^ sw));
            half8 af;
            af[0] = (_Float16)x0.x; af[1] = (_Float16)x0.y;
            af[2] = (_Float16)x0.z; af[3] = (_Float16)x0.w;
            af[4] = (_Float16)x1.x; af[5] = (_Float16)x1.y;
            af[6] = (_Float16)x1.z; af[7] = (_Float16)x1.w;
#pragma unroll
            for (int nt = 0; nt < 8; nt++)
                acc[nt] = __builtin_amdgcn_mfma_f32_16x16x32_f16(wf[nt][ks], af, acc[nt], 0, 0, 0);
        }

        // 3) loads arrived during MFMA; write them to the other buffer
        if (i < 2) {
            asm volatile("s_waitcnt vmcnt(0)" ::: "memory");
            __builtin_amdgcn_sched_barrier(0);
#pragma unroll
            for (int r = 0; r < 8; r++)
                *(float4*)(&Abuf[cur ^ 1][0] + r * 4096 + ldsoff) = g[r];
        }

        // 4) permuted packed epilogue for chunk c (4 x 16B stores)
        const int grow = c * 64 + w * 16 + lr;
        if (grow < N_NODES) {
            char* prow = (char*)P + (size_t)grow * 256;
#pragma unroll
            for (int m = 0; m < 4; m++) {
                half8 hh;
#pragma unroll
                for (int ii = 0; ii < 4; ii++) {
                    float va = acc[2 * m][ii];
                    float vb = acc[2 * m + 1][ii];
                    if (m < 2) { va += bias_[2 * m][ii]; vb += bias_[2 * m + 1][ii]; }
                    hh[ii]     = (_Float16)va;
                    hh[ii + 4] = (_Float16)vb;
                }
                *(half8*)(prow + m * 64 + q * 16) = hh;
            }
        }

        // 5) sync: ds_writes visible to all waves before next iter's reads
        asm volatile("s_waitcnt lgkmcnt(0)" ::: "memory");
        __builtin_amdgcn_s_barrier();
    }
}

// ---------------------------------------------------------------------------
__device__ inline bool detect_int64(const int* e32) {
    int orv = 0;
#pragma unroll
    for (int k = 0; k < 8; k++) orv |= e32[2 * k + 1];
    return orv == 0;
}

// ---------------------------------------------------------------------------
// Kernel 2 (R5 version, measured 22.1us): quarter-wave per edge, permuted
// W2, 16 edges per wave iteration.
// ---------------------------------------------------------------------------
__global__ __launch_bounds__(256) void edge_mlp(
    const __half* __restrict__ P,
    const void* __restrict__ eidx_raw,
    const float* __restrict__ W2,
    const float* __restrict__ b2,
    float* __restrict__ out)
{
    const int* e32 = (const int*)eidx_raw;
    const long long* e64 = (const long long*)eidx_raw;
    const bool is64 = detect_int64(e32);

    const int tid  = threadIdx.x;
    const int lane = tid & 63;
    const int j    = lane & 15;
    const int grp  = lane >> 4;
    const int hbase = ((j >> 3) << 5) + ((j & 1) << 4) + (((j >> 1) & 3) << 2);
    const float4 w2 = *(const float4*)(W2 + hbase);
    const float b2v = b2[0];

    const int gwid   = (int)((blockIdx.x * blockDim.x + tid) >> 6);
    const int nwaves = (int)((gridDim.x * blockDim.x) >> 6);

    const half4v zero = {(_Float16)0, (_Float16)0, (_Float16)0, (_Float16)0};

    for (int base = gwid * 16; base < N_EDGES; base += nwaves * 16) {
        int s[4], d[4];
#pragma unroll
        for (int u = 0; u < 4; u++) {
            const int e = base + 4 * u + grp;
            if (is64) { s[u] = (int)e64[e]; d[u] = (int)e64[N_EDGES + e]; }
            else      { s[u] = e32[e];      d[u] = e32[N_EDGES + e]; }
        }
        half4v av[4], bv[4];
#pragma unroll
        for (int u = 0; u < 4; u++) {
            av[u] = *(const half4v*)(P + (size_t)s[u] * 128 + 4 * j);
            bv[u] = *(const half4v*)(P + (size_t)d[u] * 128 + 64 + 4 * j);
        }
#pragma unroll
        for (int u = 0; u < 4; u++) {
            const half4v t = av[u] + bv[u];
            const half4v r = __builtin_elementwise_max(t, zero);
            float acc = (float)r[0] * w2.x + (float)r[1] * w2.y
                      + (float)r[2] * w2.z + (float)r[3] * w2.w;
#pragma unroll
            for (int off = 8; off >= 1; off >>= 1)
                acc += __shfl_xor(acc, off, 64);
            if (j == 0) out[base + 4 * u + grp] = acc + b2v;
        }
    }
}

// ---------------------------------------------------------------------------
// Fallback (ws too small): direct per-edge compute, slow but correct.
// ---------------------------------------------------------------------------
__global__ __launch_bounds__(256) void edge_mlp_direct(
    const float* __restrict__ node_emb,
    const void* __restrict__ eidx_raw,
    const float* __restrict__ W1,
    const float* __restrict__ b1,
    const float* __restrict__ W2,
    const float* __restrict__ b2,
    float* __restrict__ out)
{
    const int* e32 = (const int*)eidx_raw;
    const long long* e64 = (const long long*)eidx_raw;
    const bool is64 = detect_int64(e32);

    const int lane = threadIdx.x & 63;
    const float w2  = W2[lane];
    const float b2v = b2[0];
    const int gwid   = (int)((blockIdx.x * blockDim.x + threadIdx.x) >> 6);
    const int nwaves = (int)((gridDim.x * blockDim.x) >> 6);

    for (int e = gwid; e < N_EDGES; e += nwaves) {
        int s, d;
        if (is64) { s = (int)e64[e]; d = (int)e64[N_EDGES + e]; }
        else      { s = e32[e];      d = e32[N_EDGES + e]; }
        const float* es = node_emb + (size_t)s * DIM;
        const float* ed = node_emb + (size_t)d * DIM;
        float acc = b1[lane];
        for (int k = 0; k < DIM; k++) {
            acc += es[k] * W1[k * HID + lane];
            acc += ed[k] * W1[(DIM + k) * HID + lane];
        }
        float t = fmaxf(acc, 0.f) * w2;
#pragma unroll
        for (int off = 32; off >= 1; off >>= 1)
            t += __shfl_xor(t, off, 64);
        if (lane == 0) out[e] = t + b2v;
    }
}

// ---------------------------------------------------------------------------
extern "C" void kernel_launch(void* const* d_in, const int* in_sizes, int n_in,
                              void* d_out, int out_size, void* d_ws, size_t ws_size,
                              hipStream_t stream) {
    const float* node_emb = (const float*)d_in[0];
    const void*  eidx     = d_in[1];
    const float* W1       = (const float*)d_in[2];
    const float* b1       = (const float*)d_in[3];
    const float* W2       = (const float*)d_in[4];
    const float* b2       = (const float*)d_in[5];
    float* out = (float*)d_out;

    const size_t wt_off = 32u * 1024 * 1024;
    const size_t need   = wt_off + 128 * 128 * sizeof(__half);

    if (ws_size >= need) {
        __half* P   = (__half*)d_ws;
        __half* W1T = (__half*)((char*)d_ws + wt_off);
        prep_W<<<32, 256, 0, stream>>>(W1, W1T);
        precompute_P<<<521, 256, 0, stream>>>(node_emb, W1T, b1, P);
        edge_mlp<<<2048, 256, 0, stream>>>(P, eidx, W2, b2, out);
    } else {
        edge_mlp_direct<<<4096, 256, 0, stream>>>(node_emb, eidx, W1, b1, W2, b2, out);
    }
}